// Round 1
// baseline (73.475 us; speedup 1.0000x reference)
//
#include <hip/hip_runtime.h>

// out[b,c,h,w] = w[b,c] * image[b,c,h,w] + bias[b,c]
// where w/bias are gathered from dataset-1 or dataset-2 tables per sample.
//
// Memory-bound elementwise: 192 MiB in + 192 MiB out. float4-vectorized,
// one plane (1024*1024 floats = 2^18 float4) per blockIdx.y.

#define HW4 (1024 * 1024 / 4)   // float4 elements per plane

__global__ __launch_bounds__(256) void colorcal_kernel(
    const float* __restrict__ image,
    const int* __restrict__ camindex,
    const int* __restrict__ idindex,
    const int* __restrict__ dataset_type,
    const float* __restrict__ wcam1, const float* __restrict__ bcam1,
    const float* __restrict__ wident1, const float* __restrict__ bident1,
    const float* __restrict__ wcam2, const float* __restrict__ bcam2,
    const float* __restrict__ wident2, const float* __restrict__ bident2,
    float* __restrict__ out)
{
    const int plane = blockIdx.y;        // 0..47  (= b*3 + c)
    const int b = plane / 3;
    const int c = plane - b * 3;

    // Per-block-uniform scale/bias from the tiny tables (L1-resident).
    const int cam = camindex[b];
    const int id  = idindex[b];
    const int ds  = dataset_type[b];

    float w, bias;
    if (ds == 0) {
        w    = wcam1[cam * 3 + c] + wident1[id * 3 + c];
        bias = bcam1[cam * 3 + c] + bident1[id * 3 + c];
    } else {
        w    = wcam2[cam * 3 + c] + wident2[id * 3 + c];
        bias = bcam2[cam * 3 + c] + bident2[id * 3 + c];
    }

    const size_t base4 = (size_t)plane * HW4;
    const float4* __restrict__ in4  = reinterpret_cast<const float4*>(image) + base4;
    float4* __restrict__ out4 = reinterpret_cast<float4*>(out) + base4;

    const int i = blockIdx.x * blockDim.x + threadIdx.x;   // float4 index in plane
    if (i < HW4) {
        float4 v = in4[i];
        float4 r;
        r.x = fmaf(w, v.x, bias);
        r.y = fmaf(w, v.y, bias);
        r.z = fmaf(w, v.z, bias);
        r.w = fmaf(w, v.w, bias);
        out4[i] = r;
    }
}

extern "C" void kernel_launch(void* const* d_in, const int* in_sizes, int n_in,
                              void* d_out, int out_size, void* d_ws, size_t ws_size,
                              hipStream_t stream) {
    const float* image        = (const float*)d_in[0];
    const int*   camindex     = (const int*)d_in[1];
    const int*   idindex      = (const int*)d_in[2];
    const int*   dataset_type = (const int*)d_in[3];
    const float* wcam1   = (const float*)d_in[4];
    const float* bcam1   = (const float*)d_in[5];
    const float* wident1 = (const float*)d_in[6];
    const float* bident1 = (const float*)d_in[7];
    const float* wcam2   = (const float*)d_in[8];
    const float* bcam2   = (const float*)d_in[9];
    const float* wident2 = (const float*)d_in[10];
    const float* bident2 = (const float*)d_in[11];
    float* out = (float*)d_out;

    const int planes = 16 * 3;                 // B * C
    dim3 grid((HW4 + 255) / 256, planes, 1);   // 1024 x 48
    dim3 block(256, 1, 1);
    colorcal_kernel<<<grid, block, 0, stream>>>(
        image, camindex, idindex, dataset_type,
        wcam1, bcam1, wident1, bident1,
        wcam2, bcam2, wident2, bident2, out);
}

// Round 3
// 68.676 us; speedup vs baseline: 1.0699x; 1.0699x over previous
//
#include <hip/hip_runtime.h>

// out[b,c,h,w] = w[b,c] * image[b,c,h,w] + bias[b,c]
// Memory-bound elementwise: 192 MiB in + 192 MiB out.
// 4x float4 per thread (ILP), nontemporal load/store (streaming data).
// Native clang vector type (not HIP_vector_type) so the nontemporal
// builtins accept it.

typedef float fx4 __attribute__((ext_vector_type(4)));

#define HW4 (1024 * 1024 / 4)   // fx4 elements per plane (262144)
#define VPT 4                   // fx4 per thread
#define TPB 256                 // threads per block
#define TILE (TPB * VPT)        // fx4 per block tile (1024)

__global__ __launch_bounds__(TPB) void colorcal_kernel(
    const float* __restrict__ image,
    const int* __restrict__ camindex,
    const int* __restrict__ idindex,
    const int* __restrict__ dataset_type,
    const float* __restrict__ wcam1, const float* __restrict__ bcam1,
    const float* __restrict__ wident1, const float* __restrict__ bident1,
    const float* __restrict__ wcam2, const float* __restrict__ bcam2,
    const float* __restrict__ wident2, const float* __restrict__ bident2,
    float* __restrict__ out)
{
    const int plane = blockIdx.y;        // 0..47  (= b*3 + c)
    const int b = plane / 3;
    const int c = plane - b * 3;

    // Per-block-uniform scale/bias from the tiny tables (L1/L2-resident).
    const int cam = camindex[b];
    const int id  = idindex[b];
    const int ds  = dataset_type[b];

    float w, bias;
    if (ds == 0) {
        w    = wcam1[cam * 3 + c] + wident1[id * 3 + c];
        bias = bcam1[cam * 3 + c] + bident1[id * 3 + c];
    } else {
        w    = wcam2[cam * 3 + c] + wident2[id * 3 + c];
        bias = bcam2[cam * 3 + c] + bident2[id * 3 + c];
    }

    const size_t base4 = (size_t)plane * HW4 + (size_t)blockIdx.x * TILE;
    const fx4* __restrict__ in4  = reinterpret_cast<const fx4*>(image) + base4;
    fx4* __restrict__ out4 = reinterpret_cast<fx4*>(out) + base4;

    const int t = threadIdx.x;

    // Issue all loads first (4 outstanding VMEM ops per lane), then FMA+store.
    fx4 v[VPT];
#pragma unroll
    for (int k = 0; k < VPT; ++k)
        v[k] = __builtin_nontemporal_load(&in4[t + k * TPB]);

#pragma unroll
    for (int k = 0; k < VPT; ++k) {
        fx4 r;
        r.x = fmaf(w, v[k].x, bias);
        r.y = fmaf(w, v[k].y, bias);
        r.z = fmaf(w, v[k].z, bias);
        r.w = fmaf(w, v[k].w, bias);
        __builtin_nontemporal_store(r, &out4[t + k * TPB]);
    }
}

extern "C" void kernel_launch(void* const* d_in, const int* in_sizes, int n_in,
                              void* d_out, int out_size, void* d_ws, size_t ws_size,
                              hipStream_t stream) {
    const float* image        = (const float*)d_in[0];
    const int*   camindex     = (const int*)d_in[1];
    const int*   idindex      = (const int*)d_in[2];
    const int*   dataset_type = (const int*)d_in[3];
    const float* wcam1   = (const float*)d_in[4];
    const float* bcam1   = (const float*)d_in[5];
    const float* wident1 = (const float*)d_in[6];
    const float* bident1 = (const float*)d_in[7];
    const float* wcam2   = (const float*)d_in[8];
    const float* bcam2   = (const float*)d_in[9];
    const float* wident2 = (const float*)d_in[10];
    const float* bident2 = (const float*)d_in[11];
    float* out = (float*)d_out;

    const int planes = 16 * 3;                  // B * C
    dim3 grid(HW4 / TILE, planes, 1);           // 256 x 48
    dim3 block(TPB, 1, 1);
    colorcal_kernel<<<grid, block, 0, stream>>>(
        image, camindex, idindex, dataset_type,
        wcam1, bcam1, wident1, bident1,
        wcam2, bcam2, wident2, bident2, out);
}

// Round 4
// 67.031 us; speedup vs baseline: 1.0961x; 1.0245x over previous
//
#include <hip/hip_runtime.h>

// out[b,c,h,w] = w[b,c] * image[b,c,h,w] + bias[b,c]
// Memory-bound elementwise: 192 MiB in + 192 MiB out.
// 8x float4 per thread (deep VMEM ILP), nontemporal load/store (streamed once).

typedef float fx4 __attribute__((ext_vector_type(4)));

#define HW4 (1024 * 1024 / 4)   // fx4 elements per plane (262144)
#define VPT 8                   // fx4 per thread
#define TPB 256                 // threads per block
#define TILE (TPB * VPT)        // fx4 per block tile (2048)

__global__ __launch_bounds__(TPB) void colorcal_kernel(
    const float* __restrict__ image,
    const int* __restrict__ camindex,
    const int* __restrict__ idindex,
    const int* __restrict__ dataset_type,
    const float* __restrict__ wcam1, const float* __restrict__ bcam1,
    const float* __restrict__ wident1, const float* __restrict__ bident1,
    const float* __restrict__ wcam2, const float* __restrict__ bcam2,
    const float* __restrict__ wident2, const float* __restrict__ bident2,
    float* __restrict__ out)
{
    const int plane = blockIdx.y;        // 0..47  (= b*3 + c)
    const int b = plane / 3;
    const int c = plane - b * 3;

    // Per-block-uniform scale/bias from the tiny tables (L1/L2-resident).
    const int cam = camindex[b];
    const int id  = idindex[b];
    const int ds  = dataset_type[b];

    float w, bias;
    if (ds == 0) {
        w    = wcam1[cam * 3 + c] + wident1[id * 3 + c];
        bias = bcam1[cam * 3 + c] + bident1[id * 3 + c];
    } else {
        w    = wcam2[cam * 3 + c] + wident2[id * 3 + c];
        bias = bcam2[cam * 3 + c] + bident2[id * 3 + c];
    }

    const size_t base4 = (size_t)plane * HW4 + (size_t)blockIdx.x * TILE;
    const fx4* __restrict__ in4  = reinterpret_cast<const fx4*>(image) + base4;
    fx4* __restrict__ out4 = reinterpret_cast<fx4*>(out) + base4;

    const int t = threadIdx.x;

    // Issue all loads first (8 outstanding VMEM ops per lane), then FMA+store.
    fx4 v[VPT];
#pragma unroll
    for (int k = 0; k < VPT; ++k)
        v[k] = __builtin_nontemporal_load(&in4[t + k * TPB]);

#pragma unroll
    for (int k = 0; k < VPT; ++k) {
        fx4 r;
        r.x = fmaf(w, v[k].x, bias);
        r.y = fmaf(w, v[k].y, bias);
        r.z = fmaf(w, v[k].z, bias);
        r.w = fmaf(w, v[k].w, bias);
        __builtin_nontemporal_store(r, &out4[t + k * TPB]);
    }
}

extern "C" void kernel_launch(void* const* d_in, const int* in_sizes, int n_in,
                              void* d_out, int out_size, void* d_ws, size_t ws_size,
                              hipStream_t stream) {
    const float* image        = (const float*)d_in[0];
    const int*   camindex     = (const int*)d_in[1];
    const int*   idindex     = (const int*)d_in[2];
    const int*   dataset_type = (const int*)d_in[3];
    const float* wcam1   = (const float*)d_in[4];
    const float* bcam1   = (const float*)d_in[5];
    const float* wident1 = (const float*)d_in[6];
    const float* bident1 = (const float*)d_in[7];
    const float* wcam2   = (const float*)d_in[8];
    const float* bcam2   = (const float*)d_in[9];
    const float* wident2 = (const float*)d_in[10];
    const float* bident2 = (const float*)d_in[11];
    float* out = (float*)d_out;

    const int planes = 16 * 3;                  // B * C
    dim3 grid(HW4 / TILE, planes, 1);           // 128 x 48
    dim3 block(TPB, 1, 1);
    colorcal_kernel<<<grid, block, 0, stream>>>(
        image, camindex, idindex, dataset_type,
        wcam1, bcam1, wident1, bident1,
        wcam2, bcam2, wident2, bident2, out);
}